// Round 16
// baseline (693.432 us; speedup 1.0000x reference)
//
#include <hip/hip_runtime.h>

// ============================================================================
// DIAGNOSTIC ROUND: each phase kernel repeats its (idempotent) work REP_x
// times so every dispatch exceeds the ~158us harness fills and shows up in
// the rocprof top-5 with its own dur/FETCH/WRITE/VALUBusy. asm memory
// clobbers prevent the compiler from CSE-ing the repeated loads.
// Shapes fixed by the reference: B=8, S=4096, H=2048.
// ============================================================================
#define BB 8
#define SS 4096
#define HH 2048
#define TOPK 32

#define REP_DOT  8
#define REP_TOPK 6
#define REP_MIX  5

typedef float vfloat4 __attribute__((ext_vector_type(4)));

// ---------------------------------------------------------------------------
// K0: per-batch histogram (not repeated; ~4us, derivable as residual).
// ---------------------------------------------------------------------------
__global__ void hist_kernel(const int* __restrict__ pos,
                            int* __restrict__ counts) {
    __shared__ int cnt[SS];
    int b = blockIdx.x;
    int t = threadIdx.x;
    for (int i = t; i < SS; i += 256) cnt[i] = 0;
    __syncthreads();
    for (int i = t; i < SS; i += 256)
        atomicAdd(&cnt[pos[(size_t)b * SS + i]], 1);
    __syncthreads();
    for (int i = t; i < SS; i += 256)
        counts[(size_t)b * SS + i] = cnt[i];
}

// ---------------------------------------------------------------------------
// K1 x REP_DOT: one wave per row, refs only (count>0).
// ---------------------------------------------------------------------------
__global__ __launch_bounds__(256)
void dot_kernel(const float* __restrict__ base,
                const float* __restrict__ bw,
                const int* __restrict__ counts,
                float* __restrict__ d2) {
    int wid  = (blockIdx.x * 256 + threadIdx.x) >> 6;
    int lane = threadIdx.x & 63;
    if (counts[wid] == 0) return;
    int b = wid >> 12;

    const float4* rp = (const float4*)(base + (size_t)wid * HH) + lane;
    const float4* wp = (const float4*)(bw + (size_t)b * HH) + lane;

    for (int rep = 0; rep < REP_DOT; ++rep) {
        asm volatile("" ::: "memory");    // force re-load each rep
        float4 r0 = rp[0],   r1 = rp[64],  r2 = rp[128], r3 = rp[192];
        float4 r4 = rp[256], r5 = rp[320], r6 = rp[384], r7 = rp[448];
        float4 w0 = wp[0],   w1 = wp[64],  w2 = wp[128], w3 = wp[192];
        float4 w4 = wp[256], w5 = wp[320], w6 = wp[384], w7 = wp[448];

        float s0 = r0.x*w0.x + r0.y*w0.y + r0.z*w0.z + r0.w*w0.w;
        float s1 = r1.x*w1.x + r1.y*w1.y + r1.z*w1.z + r1.w*w1.w;
        float s2 = r2.x*w2.x + r2.y*w2.y + r2.z*w2.z + r2.w*w2.w;
        float s3 = r3.x*w3.x + r3.y*w3.y + r3.z*w3.z + r3.w*w3.w;
        float s4 = r4.x*w4.x + r4.y*w4.y + r4.z*w4.z + r4.w*w4.w;
        float s5 = r5.x*w5.x + r5.y*w5.y + r5.z*w5.z + r5.w*w5.w;
        float s6 = r6.x*w6.x + r6.y*w6.y + r6.z*w6.z + r6.w*w6.w;
        float s7 = r7.x*w7.x + r7.y*w7.y + r7.z*w7.z + r7.w*w7.w;
        float acc = ((s0 + s1) + (s2 + s3)) + ((s4 + s5) + (s6 + s7));

        #pragma unroll
        for (int off = 32; off > 0; off >>= 1)
            acc += __shfl_down(acc, off, 64);

        if (lane == 0) d2[wid] = acc;
    }
}

// ---------------------------------------------------------------------------
// K2 x REP_TOPK: blocks 0..7 topk; blocks 8.. copy count==0 rows (NT).
// ---------------------------------------------------------------------------
__global__ void topk_copy_kernel(const float* __restrict__ d2,
                                 const int* __restrict__ pos,
                                 const int* __restrict__ counts,
                                 const float* __restrict__ base,
                                 float* __restrict__ mixed,
                                 float* __restrict__ detect,
                                 float* __restrict__ nontopk,
                                 float* __restrict__ meanv,
                                 int nblocks) {
    __shared__ float smem[2 * SS];
    int t = threadIdx.x;

    for (int rep = 0; rep < REP_TOPK; ++rep) {
        asm volatile("" ::: "memory");
        if (blockIdx.x < BB) {
            float* dvals = smem;
            float* vals  = smem + SS;
            int b = blockIdx.x;

            __syncthreads();              // prev rep fully done before overwrite
            for (int i = t; i < SS; i += 256)
                dvals[i] = d2[(size_t)b * SS + i];
            __syncthreads();
            for (int i = t; i < SS; i += 256) {
                float v = fmaxf(dvals[pos[(size_t)b * SS + i]], 0.f);
                vals[i] = v;
                detect[(size_t)b * SS + i] = v;
            }
            __syncthreads();

            if (t < 64) {
                int lane = t;
                float sum = 0.f;
                for (int it = 0; it < TOPK; ++it) {
                    float lv = -INFINITY;
                    int   li = 0x7fffffff;
                    for (int c = lane * 4; c < SS; c += 256) {
                        float4 v = *(const float4*)&vals[c];
                        if (v.x > lv) { lv = v.x; li = c; }
                        if (v.y > lv) { lv = v.y; li = c + 1; }
                        if (v.z > lv) { lv = v.z; li = c + 2; }
                        if (v.w > lv) { lv = v.w; li = c + 3; }
                    }
                    #pragma unroll
                    for (int off = 32; off > 0; off >>= 1) {
                        float ov = __shfl_down(lv, off, 64);
                        int   oi = __shfl_down(li, off, 64);
                        if (ov > lv || (ov == lv && oi < li)) { lv = ov; li = oi; }
                    }
                    lv = __shfl(lv, 0, 64);
                    li = __shfl(li, 0, 64);
                    sum += lv;
                    if (lane == 0) vals[li] = -INFINITY;
                }
                if (lane == 0) meanv[b] = sum / (float)TOPK;
            }
            __syncthreads();
            for (int i = t; i < SS; i += 256) {
                float v = vals[i];
                nontopk[(size_t)b * SS + i] = (v == -INFINITY) ? 0.f : v;
            }
        } else {
            const int nrows = BB * SS;
            const int ncopy = nblocks - BB;
            for (int row = blockIdx.x - BB; row < nrows; row += ncopy) {
                if (counts[row] != 0) continue;
                const vfloat4* bp = (const vfloat4*)(base + (size_t)row * HH) + t;
                vfloat4*       op = (vfloat4*)(mixed + (size_t)row * HH) + t;
                vfloat4 v0 = __builtin_nontemporal_load(bp);
                vfloat4 v1 = __builtin_nontemporal_load(bp + 256);
                __builtin_nontemporal_store(v0, op);
                __builtin_nontemporal_store(v1, op + 256);
            }
        }
    }
}

// ---------------------------------------------------------------------------
// K3 x REP_MIX: 4 rows/block, refs only; plain loads, NT stores.
// ---------------------------------------------------------------------------
__global__ void mix_kernel(const float* __restrict__ base,
                           const float* __restrict__ bw,
                           const int* __restrict__ counts,
                           const float* __restrict__ meanv,
                           float* __restrict__ mixed) {
    int r0 = blockIdx.x << 2;
    int b  = r0 >> 12;
    const float4* w4 = (const float4*)(bw + (size_t)b * HH);
    int t = threadIdx.x;

    for (int rep = 0; rep < REP_MIX; ++rep) {
        asm volatile("" ::: "memory");
        float mb = meanv[b];
        #pragma unroll
        for (int k = 0; k < 4; ++k) {
            int r = r0 + k;
            int c = counts[r];
            if (c == 0) continue;
            float scale = (float)c * mb;
            const float4* b4 = (const float4*)(base + (size_t)r * HH) + t;
            vfloat4*      o4 = (vfloat4*)(mixed + (size_t)r * HH) + t;
            float4 v0 = b4[0];
            float4 v1 = b4[256];
            float4 wv0 = w4[t];
            float4 wv1 = w4[t + 256];
            vfloat4 o0, o1;
            o0.x = v0.x + scale * wv0.x;
            o0.y = v0.y + scale * wv0.y;
            o0.z = v0.z + scale * wv0.z;
            o0.w = v0.w + scale * wv0.w;
            o1.x = v1.x + scale * wv1.x;
            o1.y = v1.y + scale * wv1.y;
            o1.z = v1.z + scale * wv1.z;
            o1.w = v1.w + scale * wv1.w;
            __builtin_nontemporal_store(o0, o4);
            __builtin_nontemporal_store(o1, o4 + 256);
        }
    }
}

// ---------------------------------------------------------------------------
extern "C" void kernel_launch(void* const* d_in, const int* in_sizes, int n_in,
                              void* d_out, int out_size, void* d_ws, size_t ws_size,
                              hipStream_t stream) {
    const float* base = (const float*)d_in[0];
    const int*   pos  = (const int*)d_in[1];
    const float* bw   = (const float*)d_in[2];

    float* out_mixed   = (float*)d_out;
    float* out_detect  = out_mixed + (size_t)BB * SS * HH;
    float* out_nontopk = out_detect + (size_t)BB * SS;

    int*   counts = (int*)d_ws;
    float* d2     = (float*)((char*)d_ws + (size_t)BB * SS * sizeof(int));
    float* meanv  = (float*)((char*)d_ws + 2 * (size_t)BB * SS * sizeof(int));

    const int nrows = BB * SS;
    const int nk2   = BB + 1024;

    hist_kernel<<<BB, 256, 0, stream>>>(pos, counts);
    dot_kernel<<<nrows / 4, 256, 0, stream>>>(base, bw, counts, d2);
    topk_copy_kernel<<<nk2, 256, 0, stream>>>(
        d2, pos, counts, base, out_mixed, out_detect, out_nontopk, meanv, nk2);
    mix_kernel<<<nrows / 4, 256, 0, stream>>>(base, bw, counts, meanv, out_mixed);
}

// Round 17
// 173.835 us; speedup vs baseline: 3.9890x; 3.9890x over previous
//
#include <hip/hip_runtime.h>

// Shapes fixed by the reference: B=8, S=4096, H=2048.
#define BB 8
#define SS 4096
#define HH 2048
#define TOPK 32

typedef float vfloat4 __attribute__((ext_vector_type(4)));

// ---------------------------------------------------------------------------
// K0: per-batch histogram of pos -> counts. B blocks, LDS atomics. ~4us.
// ---------------------------------------------------------------------------
__global__ void hist_kernel(const int* __restrict__ pos,
                            int* __restrict__ counts) {
    __shared__ int cnt[SS];
    int b = blockIdx.x;
    int t = threadIdx.x;
    for (int i = t; i < SS; i += 256) cnt[i] = 0;
    __syncthreads();
    for (int i = t; i < SS; i += 256)
        atomicAdd(&cnt[pos[(size_t)b * SS + i]], 1);
    __syncthreads();
    for (int i = t; i < SS; i += 256)
        counts[(size_t)b * SS + i] = cnt[i];
}

// ---------------------------------------------------------------------------
// K1: one wave per row; dot ONLY for referenced rows (count>0, ~63%).
// Full-unroll: 16 loads up-front, FMA tree, shuffle reduce. ~40us (R16).
// ---------------------------------------------------------------------------
__global__ __launch_bounds__(256)
void dot_kernel(const float* __restrict__ base,
                const float* __restrict__ bw,
                const int* __restrict__ counts,
                float* __restrict__ d2) {
    int wid  = (blockIdx.x * 256 + threadIdx.x) >> 6;
    int lane = threadIdx.x & 63;
    if (counts[wid] == 0) return;
    int b = wid >> 12;

    const float4* rp = (const float4*)(base + (size_t)wid * HH) + lane;
    const float4* wp = (const float4*)(bw + (size_t)b * HH) + lane;

    float4 r0 = rp[0],   r1 = rp[64],  r2 = rp[128], r3 = rp[192];
    float4 r4 = rp[256], r5 = rp[320], r6 = rp[384], r7 = rp[448];
    float4 w0 = wp[0],   w1 = wp[64],  w2 = wp[128], w3 = wp[192];
    float4 w4 = wp[256], w5 = wp[320], w6 = wp[384], w7 = wp[448];

    float s0 = r0.x*w0.x + r0.y*w0.y + r0.z*w0.z + r0.w*w0.w;
    float s1 = r1.x*w1.x + r1.y*w1.y + r1.z*w1.z + r1.w*w1.w;
    float s2 = r2.x*w2.x + r2.y*w2.y + r2.z*w2.z + r2.w*w2.w;
    float s3 = r3.x*w3.x + r3.y*w3.y + r3.z*w3.z + r3.w*w3.w;
    float s4 = r4.x*w4.x + r4.y*w4.y + r4.z*w4.z + r4.w*w4.w;
    float s5 = r5.x*w5.x + r5.y*w5.y + r5.z*w5.z + r5.w*w5.w;
    float s6 = r6.x*w6.x + r6.y*w6.y + r6.z*w6.z + r6.w*w6.w;
    float s7 = r7.x*w7.x + r7.y*w7.y + r7.z*w7.z + r7.w*w7.w;
    float acc = ((s0 + s1) + (s2 + s3)) + ((s4 + s5) + (s6 + s7));

    #pragma unroll
    for (int off = 32; off > 0; off >>= 1)
        acc += __shfl_down(acc, off, 64);

    if (lane == 0) d2[wid] = acc;
}

// ---------------------------------------------------------------------------
// K2: blocks 0..7: per-batch topk (gather d2 DIRECTLY from global -- the
//     16KB/batch d2 slab is L1/L2-resident, no LDS staging; LDS now 16KB
//     so copy blocks reach 8 blocks/CU).
//     blocks 8..8199: copy mixed=base for count==0 rows, MIX-SHAPED: 4
//     contiguous rows per block, one int4 counts load, NT both ways.
//     (R16 diagnostic: mix-shaped NT streaming = 5.4 TB/s; the old strided
//     1024-block copy loop = 1.3 TB/s. Structure, not store policy.)
// ---------------------------------------------------------------------------
__global__ __launch_bounds__(256)
void topk_copy_kernel(const float* __restrict__ d2,
                      const int* __restrict__ pos,
                      const int* __restrict__ counts,
                      const float* __restrict__ base,
                      float* __restrict__ mixed,
                      float* __restrict__ detect,
                      float* __restrict__ nontopk,
                      float* __restrict__ meanv) {
    __shared__ float vals[SS];            // 16 KB
    int t = threadIdx.x;

    if (blockIdx.x < BB) {
        int b = blockIdx.x;
        for (int i = t; i < SS; i += 256) {
            float v = fmaxf(d2[(size_t)b * SS + pos[(size_t)b * SS + i]], 0.f);
            vals[i] = v;
            detect[(size_t)b * SS + i] = v;
        }
        __syncthreads();

        if (t < 64) {                     // single wave: barrier-free top-k
            int lane = t;
            float sum = 0.f;
            for (int it = 0; it < TOPK; ++it) {
                float lv = -INFINITY;
                int   li = 0x7fffffff;
                for (int c = lane * 4; c < SS; c += 256) {
                    float4 v = *(const float4*)&vals[c];
                    if (v.x > lv) { lv = v.x; li = c; }
                    if (v.y > lv) { lv = v.y; li = c + 1; }
                    if (v.z > lv) { lv = v.z; li = c + 2; }
                    if (v.w > lv) { lv = v.w; li = c + 3; }
                }
                #pragma unroll
                for (int off = 32; off > 0; off >>= 1) {
                    float ov = __shfl_down(lv, off, 64);
                    int   oi = __shfl_down(li, off, 64);
                    if (ov > lv || (ov == lv && oi < li)) { lv = ov; li = oi; }
                }
                lv = __shfl(lv, 0, 64);
                li = __shfl(li, 0, 64);
                sum += lv;
                if (lane == 0) vals[li] = -INFINITY;  // wave-synchronous
            }
            if (lane == 0) meanv[b] = sum / (float)TOPK;
        }
        __syncthreads();
        for (int i = t; i < SS; i += 256) {
            float v = vals[i];
            nontopk[(size_t)b * SS + i] = (v == -INFINITY) ? 0.f : v;
        }
    } else {
        int r0 = (blockIdx.x - BB) << 2;  // 4 contiguous rows
        int4 c4 = *(const int4*)&counts[r0];
        #pragma unroll
        for (int k = 0; k < 4; ++k) {
            int c = (k == 0) ? c4.x : (k == 1) ? c4.y : (k == 2) ? c4.z : c4.w;
            if (c != 0) continue;         // referenced rows handled by mix
            const vfloat4* bp = (const vfloat4*)(base + (size_t)(r0 + k) * HH) + t;
            vfloat4*       op = (vfloat4*)(mixed + (size_t)(r0 + k) * HH) + t;
            vfloat4 v0 = __builtin_nontemporal_load(bp);
            vfloat4 v1 = __builtin_nontemporal_load(bp + 256);
            __builtin_nontemporal_store(v0, op);
            __builtin_nontemporal_store(v1, op + 256);
        }
    }
}

// ---------------------------------------------------------------------------
// K3: 4 contiguous rows per block; ONLY count>0 rows (~63%):
//   mixed[b,p,:] = base[b,p,:] + counts[b,p]*mean[b]*W[b,:]
// Plain loads (L3 hits from dot), NT stores. (R16: ~30us, 5.4 TB/s.)
// ---------------------------------------------------------------------------
__global__ __launch_bounds__(256)
void mix_kernel(const float* __restrict__ base,
                const float* __restrict__ bw,
                const int* __restrict__ counts,
                const float* __restrict__ meanv,
                float* __restrict__ mixed) {
    int r0 = blockIdx.x << 2;
    int b  = r0 >> 12;
    const float4* w4 = (const float4*)(bw + (size_t)b * HH);
    float mb = meanv[b];
    int t = threadIdx.x;
    int4 c4 = *(const int4*)&counts[r0];

    float4 wv0 = w4[t];
    float4 wv1 = w4[t + 256];

    #pragma unroll
    for (int k = 0; k < 4; ++k) {
        int c = (k == 0) ? c4.x : (k == 1) ? c4.y : (k == 2) ? c4.z : c4.w;
        if (c == 0) continue;             // copied by K2
        float scale = (float)c * mb;
        const float4* b4 = (const float4*)(base + (size_t)(r0 + k) * HH) + t;
        vfloat4*      o4 = (vfloat4*)(mixed + (size_t)(r0 + k) * HH) + t;
        float4 v0 = b4[0];
        float4 v1 = b4[256];
        vfloat4 o0, o1;
        o0.x = v0.x + scale * wv0.x;
        o0.y = v0.y + scale * wv0.y;
        o0.z = v0.z + scale * wv0.z;
        o0.w = v0.w + scale * wv0.w;
        o1.x = v1.x + scale * wv1.x;
        o1.y = v1.y + scale * wv1.y;
        o1.z = v1.z + scale * wv1.z;
        o1.w = v1.w + scale * wv1.w;
        __builtin_nontemporal_store(o0, o4);
        __builtin_nontemporal_store(o1, o4 + 256);
    }
}

// ---------------------------------------------------------------------------
extern "C" void kernel_launch(void* const* d_in, const int* in_sizes, int n_in,
                              void* d_out, int out_size, void* d_ws, size_t ws_size,
                              hipStream_t stream) {
    const float* base = (const float*)d_in[0];
    const int*   pos  = (const int*)d_in[1];
    const float* bw   = (const float*)d_in[2];

    float* out_mixed   = (float*)d_out;
    float* out_detect  = out_mixed + (size_t)BB * SS * HH;
    float* out_nontopk = out_detect + (size_t)BB * SS;

    int*   counts = (int*)d_ws;
    float* d2     = (float*)((char*)d_ws + (size_t)BB * SS * sizeof(int));
    float* meanv  = (float*)((char*)d_ws + 2 * (size_t)BB * SS * sizeof(int));

    const int nrows = BB * SS;

    hist_kernel<<<BB, 256, 0, stream>>>(pos, counts);
    dot_kernel<<<nrows / 4, 256, 0, stream>>>(base, bw, counts, d2);
    topk_copy_kernel<<<BB + nrows / 4, 256, 0, stream>>>(
        d2, pos, counts, base, out_mixed, out_detect, out_nontopk, meanv);
    mix_kernel<<<nrows / 4, 256, 0, stream>>>(base, bw, counts, meanv, out_mixed);
}